// Round 1
// baseline (177.018 us; speedup 1.0000x reference)
//
#include <hip/hip_runtime.h>
#include <math.h>

#define NQ   1280
#define DD   256
#define CIN  64
#define HH   200
#define WW   200

// Kernel 1: one block per batch. Computes t[b, 0..255] =
//   aws[b] * (out_w @ s[b]) + out_b,  where s[b,c] is the bilinear-blended,
//   ReLU'd 3x3 conv output at the (single) per-batch grid point.
__global__ __launch_bounds__(256) void per_batch_kernel(
    const float* __restrict__ navi,    // (B,2)
    const float* __restrict__ bev,     // (B,64,H,W)
    const float* __restrict__ pscore,  // (B,2)
    const float* __restrict__ aws_w,   // (256,)
    const float* __restrict__ aws_b,   // (1,)
    const float* __restrict__ conv_w,  // (256,64,3,3)
    const float* __restrict__ conv_b,  // (256,)
    const float* __restrict__ out_w,   // (256,256)
    const float* __restrict__ out_b,   // (256,)
    float* __restrict__ t_out)         // (B,256)
{
    const int b = blockIdx.x;
    const int tid = threadIdx.x;

    __shared__ float win[CIN][16];   // 4x4 spatial window per input channel
    __shared__ float s_s[DD];        // blended sampled value per out channel
    __shared__ float red[DD];        // reduction buffer for aws

    // ---- per-batch sample point (same for all 1280 queries) ----
    float nx = navi[b * 2 + 0];
    float ny = navi[b * 2 + 1];
    // grid = (navi_y/32, navi_x/32); align_corners=False mapping
    float gx = (ny / 32.0f + 1.0f) * 0.5f * (float)WW - 0.5f;
    float gy = (nx / 32.0f + 1.0f) * 0.5f * (float)HH - 0.5f;
    float x0f = floorf(gx);
    float y0f = floorf(gy);
    float wx1 = gx - x0f;
    float wy1 = gy - y0f;
    int x0 = (int)x0f;
    int y0 = (int)y0f;

    // corner weights * validity (zeros padding)
    float cw[4];
    {
        float wx[2] = {1.0f - wx1, wx1};
        float wy[2] = {1.0f - wy1, wy1};
#pragma unroll
        for (int k = 0; k < 4; ++k) {
            int dx = k & 1, dy = k >> 1;
            float ixf = x0f + (float)dx, iyf = y0f + (float)dy;
            bool valid = (ixf >= 0.0f) && (ixf <= (float)(WW - 1)) &&
                         (iyf >= 0.0f) && (iyf <= (float)(HH - 1));
            cw[k] = wx[dx] * wy[dy] * (valid ? 1.0f : 0.0f);
        }
    }

    // ---- stage 4x4 bev window (zero-padded) for all 64 input channels ----
    for (int idx = tid; idx < CIN * 16; idx += 256) {
        int ci = idx >> 4;
        int pos = idx & 15;
        int yy = y0 - 1 + (pos >> 2);
        int xx = x0 - 1 + (pos & 3);
        float v = 0.0f;
        if (yy >= 0 && yy < HH && xx >= 0 && xx < WW)
            v = bev[((size_t)b * CIN + ci) * (HH * WW) + (size_t)yy * WW + xx];
        win[ci][pos] = v;
    }

    // ---- aws scalar: sine-embed(point_score) . aws_w + aws_b ----
    {
        float psx = pscore[b * 2 + 0];
        float psy = pscore[b * 2 + 1];
        float p = (tid < 128) ? psy : psx;    // concat([embed(y), embed(x)])
        int j = (tid & 127) >> 1;
        float dimt = powf(10000.0f, (float)j / 64.0f);
        float arg = p * 6.283185307179586f / dimt;
        float e = (tid & 1) ? cosf(arg) : sinf(arg);
        red[tid] = e * aws_w[tid];
    }

    __syncthreads();

    // ---- 3x3 conv (64->256) at the 4 corners, channel c = tid ----
    {
        const int c = tid;
        float acc0 = 0.f, acc1 = 0.f, acc2 = 0.f, acc3 = 0.f;
        const float* wp = conv_w + (size_t)c * (CIN * 9);
        for (int ci = 0; ci < CIN; ++ci) {
            const float* wr = win[ci];
#pragma unroll
            for (int ky = 0; ky < 3; ++ky) {
#pragma unroll
                for (int kx = 0; kx < 3; ++kx) {
                    float w = wp[ci * 9 + ky * 3 + kx];
                    acc0 += w * wr[ky * 4 + kx];            // (y0,   x0)
                    acc1 += w * wr[ky * 4 + kx + 1];        // (y0,   x0+1)
                    acc2 += w * wr[(ky + 1) * 4 + kx];      // (y0+1, x0)
                    acc3 += w * wr[(ky + 1) * 4 + kx + 1];  // (y0+1, x0+1)
                }
            }
        }
        float cb = conv_b[c];
        float v0 = fmaxf(acc0 + cb, 0.0f);
        float v1 = fmaxf(acc1 + cb, 0.0f);
        float v2 = fmaxf(acc2 + cb, 0.0f);
        float v3 = fmaxf(acc3 + cb, 0.0f);
        s_s[c] = cw[0] * v0 + cw[1] * v1 + cw[2] * v2 + cw[3] * v3;
    }

    __syncthreads();

    // tree-reduce red[] for aws
    for (int off = 128; off > 0; off >>= 1) {
        if (tid < off) red[tid] += red[tid + off];
        __syncthreads();
    }
    float aws = red[0] + aws_b[0];

    // ---- matvec: t[d] = aws * sum_c out_w[d,c]*s[c] + out_b[d] ----
    {
        const int d = tid;
        const float4* wr = (const float4*)(out_w + (size_t)d * DD);
        float sum = 0.0f;
#pragma unroll 4
        for (int c4 = 0; c4 < DD / 4; ++c4) {
            float4 w4 = wr[c4];
            sum += w4.x * s_s[c4 * 4 + 0] + w4.y * s_s[c4 * 4 + 1] +
                   w4.z * s_s[c4 * 4 + 2] + w4.w * s_s[c4 * 4 + 3];
        }
        t_out[b * DD + d] = aws * sum + out_b[d];
    }
}

// Kernel 2: out[b,q,d] = queries[b,q,d] + t[b,d]  (float4-vectorized)
__global__ __launch_bounds__(256) void add_kernel(
    const float4* __restrict__ q4,
    const float4* __restrict__ t4,   // (B, 64) float4
    float4* __restrict__ out4,
    int total4)
{
    int i = blockIdx.x * blockDim.x + threadIdx.x;
    if (i >= total4) return;
    float4 v = q4[i];
    int d4 = i & (DD / 4 - 1);
    int b = i / (NQ * DD / 4);
    float4 tv = t4[b * (DD / 4) + d4];
    v.x += tv.x; v.y += tv.y; v.z += tv.z; v.w += tv.w;
    out4[i] = v;
}

extern "C" void kernel_launch(void* const* d_in, const int* in_sizes, int n_in,
                              void* d_out, int out_size, void* d_ws, size_t ws_size,
                              hipStream_t stream) {
    const float* queries = (const float*)d_in[0];   // (B,NQ,256)
    const float* navi    = (const float*)d_in[1];   // (B,2)
    const float* bev     = (const float*)d_in[2];   // (B,64,200,200)
    // d_in[3] spatial_shape (int32) — values are (200,200), unused
    const float* pscore  = (const float*)d_in[4];   // (B,2)
    // d_in[5] aw_w, d_in[6] aw_b — dead code (softmax over size-1 axis == 1)
    const float* aws_w   = (const float*)d_in[7];   // (1,256)
    const float* aws_b   = (const float*)d_in[8];   // (1,)
    const float* conv_w  = (const float*)d_in[9];   // (256,64,3,3)
    const float* conv_b  = (const float*)d_in[10];  // (256,)
    const float* out_w   = (const float*)d_in[11];  // (256,256)
    const float* out_b   = (const float*)d_in[12];  // (256,)
    float* out = (float*)d_out;
    float* t   = (float*)d_ws;                      // (B,256) scratch

    const int B = in_sizes[1] / 2;                  // 8

    per_batch_kernel<<<B, 256, 0, stream>>>(navi, bev, pscore, aws_w, aws_b,
                                            conv_w, conv_b, out_w, out_b, t);

    int total4 = B * NQ * DD / 4;
    add_kernel<<<(total4 + 255) / 256, 256, 0, stream>>>(
        (const float4*)queries, (const float4*)t, (float4*)out, total4);
}

// Round 2
// 145.576 us; speedup vs baseline: 1.2160x; 1.2160x over previous
//
#include <hip/hip_runtime.h>
#include <math.h>

#define NQ   1280
#define DD   256
#define CIN  64
#define HH   200
#define WW   200
#define KW   576   // CIN * 9 taps per output channel

__device__ __forceinline__ float wave_reduce(float v) {
#pragma unroll
    for (int off = 32; off > 0; off >>= 1) v += __shfl_down(v, off, 64);
    return v;
}

// Kernel A: grid = B*64 blocks, 4 waves each; one wave per conv output channel.
// Computes s[b,c] = bilinear-blend of ReLU(conv3x3(bev)[c]) at the per-batch
// grid point; cg==0 blocks additionally compute aws[b].
__global__ __launch_bounds__(256) void conv_sample_kernel(
    const float* __restrict__ navi,    // (B,2)
    const float* __restrict__ bev,     // (B,64,H,W)
    const float* __restrict__ pscore,  // (B,2)
    const float* __restrict__ aws_w,   // (256,)
    const float* __restrict__ aws_b,   // (1,)
    const float* __restrict__ conv_w,  // (256,64,3,3)
    const float* __restrict__ conv_b,  // (256,)
    float* __restrict__ s_out,         // (B,256)
    float* __restrict__ aws_out)       // (B,)
{
    const int b    = blockIdx.x >> 6;
    const int cg   = blockIdx.x & 63;
    const int tid  = threadIdx.x;
    const int lane = tid & 63;
    const int wave = tid >> 6;

    __shared__ float win[CIN][16];  // 4x4 zero-padded window per in-channel
    __shared__ float wv[4][KW];     // per-corner, weight-ordered window copies
    __shared__ float red[DD];       // aws reduction

    // ---- per-batch sample point ----
    float nx = navi[b * 2 + 0];
    float ny = navi[b * 2 + 1];
    float gx = (ny * (1.0f / 32.0f) + 1.0f) * 0.5f * (float)WW - 0.5f;
    float gy = (nx * (1.0f / 32.0f) + 1.0f) * 0.5f * (float)HH - 0.5f;
    float x0f = floorf(gx), y0f = floorf(gy);
    float wx1 = gx - x0f, wy1 = gy - y0f;
    int x0 = (int)x0f, y0 = (int)y0f;

    float cw[4];
    {
        float wx[2] = {1.0f - wx1, wx1};
        float wy[2] = {1.0f - wy1, wy1};
#pragma unroll
        for (int k = 0; k < 4; ++k) {
            int dx = k & 1, dy = k >> 1;
            float ixf = x0f + (float)dx, iyf = y0f + (float)dy;
            bool valid = (ixf >= 0.0f) && (ixf <= (float)(WW - 1)) &&
                         (iyf >= 0.0f) && (iyf <= (float)(HH - 1));
            cw[k] = wx[dx] * wy[dy] * (valid ? 1.0f : 0.0f);
        }
    }

    // ---- stage 4x4 window ----
    for (int idx = tid; idx < CIN * 16; idx += 256) {
        int ci = idx >> 4, pos = idx & 15;
        int yy = y0 - 1 + (pos >> 2);
        int xx = x0 - 1 + (pos & 3);
        float v = 0.0f;
        if (yy >= 0 && yy < HH && xx >= 0 && xx < WW)
            v = bev[((size_t)b * CIN + ci) * (HH * WW) + (size_t)yy * WW + xx];
        win[ci][pos] = v;
    }
    __syncthreads();

    // expand: wv[corner][ci*9 + ky*3 + kx] = win[ci][(ky+dy)*4 + (kx+dx)]
    for (int idx = tid; idx < 4 * KW; idx += 256) {
        int corner = idx / KW, k = idx - corner * KW;
        int ci = k / 9, r = k - ci * 9;
        int ky = r / 3, kx = r - ky * 3;
        int dy = corner >> 1, dx = corner & 1;
        wv[corner][k] = win[ci][(ky + dy) * 4 + (kx + dx)];
    }
    __syncthreads();

    // ---- one wave per output channel, coalesced conv_w reads ----
    const int c = cg * 4 + wave;
    const float* wp = conv_w + (size_t)c * KW;
    float a0 = 0.f, a1 = 0.f, a2 = 0.f, a3 = 0.f;
#pragma unroll
    for (int i = 0; i < 9; ++i) {
        float w = wp[i * 64 + lane];
        a0 = fmaf(w, wv[0][i * 64 + lane], a0);
        a1 = fmaf(w, wv[1][i * 64 + lane], a1);
        a2 = fmaf(w, wv[2][i * 64 + lane], a2);
        a3 = fmaf(w, wv[3][i * 64 + lane], a3);
    }
    a0 = wave_reduce(a0);
    a1 = wave_reduce(a1);
    a2 = wave_reduce(a2);
    a3 = wave_reduce(a3);
    if (lane == 0) {
        float cb = conv_b[c];
        float v0 = fmaxf(a0 + cb, 0.0f);
        float v1 = fmaxf(a1 + cb, 0.0f);
        float v2 = fmaxf(a2 + cb, 0.0f);
        float v3 = fmaxf(a3 + cb, 0.0f);
        s_out[b * DD + c] = cw[0] * v0 + cw[1] * v1 + cw[2] * v2 + cw[3] * v3;
    }

    // ---- aws[b] (block-uniform branch; one block per batch) ----
    if (cg == 0) {
        float psx = pscore[b * 2 + 0];
        float psy = pscore[b * 2 + 1];
        float p = (tid < 128) ? psy : psx;  // concat([embed(y), embed(x)])
        int j = (tid & 127) >> 1;
        float dimt = powf(10000.0f, (float)j * (1.0f / 64.0f));
        float arg = p * 6.283185307179586f / dimt;
        float e = (tid & 1) ? cosf(arg) : sinf(arg);
        red[tid] = e * aws_w[tid];
        __syncthreads();
        for (int off = 128; off > 0; off >>= 1) {
            if (tid < off) red[tid] += red[tid + off];
            __syncthreads();
        }
        if (tid == 0) aws_out[b] = red[0] + aws_b[0];
    }
}

// Kernel B: grid = B*64 blocks, one wave per output dim.
// t[b,d] = aws[b] * dot(out_w[d,:], s[b,:]) + out_b[d]
__global__ __launch_bounds__(256) void matvec_kernel(
    const float* __restrict__ out_w,   // (256,256)
    const float* __restrict__ out_b,   // (256,)
    const float* __restrict__ s_in,    // (B,256)
    const float* __restrict__ aws_in,  // (B,)
    float* __restrict__ t_out)         // (B,256)
{
    const int b    = blockIdx.x >> 6;
    const int cg   = blockIdx.x & 63;
    const int tid  = threadIdx.x;
    const int lane = tid & 63;
    const int wave = tid >> 6;

    __shared__ float s_sh[DD];
    s_sh[tid] = s_in[b * DD + tid];
    __syncthreads();

    const int d = cg * 4 + wave;
    const float* wp = out_w + (size_t)d * DD;
    float sum = 0.0f;
#pragma unroll
    for (int i = 0; i < 4; ++i)
        sum = fmaf(wp[i * 64 + lane], s_sh[i * 64 + lane], sum);
    sum = wave_reduce(sum);
    if (lane == 0) t_out[b * DD + d] = aws_in[b] * sum + out_b[d];
}

// Kernel C: out[b,q,d] = queries[b,q,d] + t[b,d]  (float4-vectorized)
__global__ __launch_bounds__(256) void add_kernel(
    const float4* __restrict__ q4,
    const float4* __restrict__ t4,   // (B, 64) float4
    float4* __restrict__ out4,
    int total4)
{
    int i = blockIdx.x * blockDim.x + threadIdx.x;
    if (i >= total4) return;
    float4 v = q4[i];
    int d4 = i & (DD / 4 - 1);
    int b = i / (NQ * DD / 4);
    float4 tv = t4[b * (DD / 4) + d4];
    v.x += tv.x; v.y += tv.y; v.z += tv.z; v.w += tv.w;
    out4[i] = v;
}

extern "C" void kernel_launch(void* const* d_in, const int* in_sizes, int n_in,
                              void* d_out, int out_size, void* d_ws, size_t ws_size,
                              hipStream_t stream) {
    const float* queries = (const float*)d_in[0];   // (B,NQ,256)
    const float* navi    = (const float*)d_in[1];   // (B,2)
    const float* bev     = (const float*)d_in[2];   // (B,64,200,200)
    // d_in[3] spatial_shape — unused (values 200,200)
    const float* pscore  = (const float*)d_in[4];   // (B,2)
    // d_in[5] aw_w, d_in[6] aw_b — dead (softmax over size-1 axis == 1)
    const float* aws_w   = (const float*)d_in[7];   // (1,256)
    const float* aws_b   = (const float*)d_in[8];   // (1,)
    const float* conv_w  = (const float*)d_in[9];   // (256,64,3,3)
    const float* conv_b  = (const float*)d_in[10];  // (256,)
    const float* out_w   = (const float*)d_in[11];  // (256,256)
    const float* out_b   = (const float*)d_in[12];  // (256,)
    float* out = (float*)d_out;

    const int B = in_sizes[1] / 2;                  // 8

    // workspace layout (floats): s[B*256] | aws[B] | pad | t[B*256]
    float* s   = (float*)d_ws;
    float* aws = s + B * DD;
    float* t   = s + B * DD + 256;                  // 16B-aligned

    conv_sample_kernel<<<B * 64, 256, 0, stream>>>(navi, bev, pscore, aws_w,
                                                   aws_b, conv_w, conv_b, s, aws);
    matvec_kernel<<<B * 64, 256, 0, stream>>>(out_w, out_b, s, aws, t);

    int total4 = B * NQ * DD / 4;
    add_kernel<<<(total4 + 255) / 256, 256, 0, stream>>>(
        (const float4*)queries, (const float4*)t, (float4*)out, total4);
}